// Round 16
// baseline (81.464 us; speedup 1.0000x reference)
//
#include <hip/hip_runtime.h>
#include <hip/hip_bf16.h>
#include <hip/hip_fp16.h>

#define TH 8
#define TW 64        // w extent per tile (2 voxels per lane)
#define DC 8
#define PH (TH+2)    // 10
#define PW (TW+2)    // 66
#define PN (PH*PW)   // 660

#define DIM_D 128
#define DIM_H 192
#define DIM_W 192
#define NREP 16      // gacc replicas (atomic spread)

#define LOG2E 1.4426950408889634f
#define LN2   0.6931471805599453f

__device__ __forceinline__ float ex2(float x){ return __builtin_amdgcn_exp2f(x); }
__device__ __forceinline__ float lg2(float x){ return __builtin_amdgcn_logf(x); }
__device__ __forceinline__ float rcpf_(float x){ return __builtin_amdgcn_rcpf(x); }
__device__ __forceinline__ __half2 bch2(unsigned u){ return __builtin_bit_cast(__half2, u); }
__device__ __forceinline__ unsigned h2u(__half2 h){ return __builtin_bit_cast(unsigned, h); }

// packed per-plane state: __half2 = (yb, tg); s1/s2 are yb-only Sobel partials.
// f16 yb (rel err 5e-4) -> z err ~5e-5; tg channel exact {0,1}.
struct PairH { __half2 u0[2], u1[2], u2[2]; float s1[2], s2[2]; };

__device__ __forceinline__ PairH calc_pair(const unsigned* __restrict__ spu, int ty, int tx)
{
    const float S30 = 47.f/256.f, S31 = 162.f/256.f;
    __half2 c[3][4];
    #pragma unroll
    for (int r = 0; r < 3; ++r) {
        const unsigned* row = spu + (ty+r)*PW + 2*tx;   // 8B-aligned (index even)
        uint2 lo = *reinterpret_cast<const uint2*>(row);
        uint2 hi = *reinterpret_cast<const uint2*>(row + 2);
        c[r][0]=bch2(lo.x); c[r][1]=bch2(lo.y); c[r][2]=bch2(hi.x); c[r][3]=bch2(hi.y);
    }
    __half2 s[4], m[4]; float dj[4];
    #pragma unroll
    for (int j = 0; j < 4; ++j) {
        s[j] = __hadd2(c[0][j], c[2][j]);
        m[j] = c[1][j];
        dj[j] = __low2float(__hsub2(c[0][j], c[2][j]));   // yb vertical diff
    }
    PairH P;
    __half2 mm02 = __hadd2(m[0], m[2]), mm13 = __hadd2(m[1], m[3]);
    P.u0[0] = m[1];                 P.u0[1] = m[2];
    P.u1[0] = __hadd2(s[1], mm02);  P.u1[1] = __hadd2(s[2], mm13);
    P.u2[0] = __hadd2(s[0], s[2]);  P.u2[1] = __hadd2(s[1], s[3]);
    float s0x=__low2float(s[0]), s1x=__low2float(s[1]), s2x=__low2float(s[2]), s3x=__low2float(s[3]);
    float m0x=__low2float(m[0]), m1x=__low2float(m[1]), m2x=__low2float(m[2]), m3x=__low2float(m[3]);
    P.s1[0] = S30*(s0x - s2x) + S31*(m0x - m2x);
    P.s1[1] = S30*(s1x - s3x) + S31*(m1x - m3x);
    P.s2[0] = S30*(dj[0] + dj[2]) + S31*dj[1];
    P.s2[1] = S30*(dj[1] + dj[3]) + S31*dj[2];
    return P;
}

__global__ __launch_bounds__(256) void lumen_main(
    const float* __restrict__ x_in, const float* __restrict__ y_out,
    const float* __restrict__ y_tg, double* __restrict__ gacc,
    float* __restrict__ dice_i, float* __restrict__ dice_c)
{
    __shared__ unsigned ring[4][PN];   // half2-packed (yb,tg); 10,560 B

    const int tid = threadIdx.x;
    const int b  = blockIdx.z >> 4;              // 16 d-tiles of DC=8
    const int d0 = (blockIdx.z & 15) * DC;
    const int h0 = blockIdx.y * TH;
    const int w0 = blockIdx.x * TW;
    const unsigned base = (unsigned)b * (unsigned)(DIM_D*DIM_H*DIM_W);
    const unsigned PL = DIM_H*DIM_W;
    const int rep = (blockIdx.x + gridDim.x*(blockIdx.y + gridDim.y*blockIdx.z)) & (NREP-1);

    // ---- staging map: thread handles halo elems tid, tid+256, tid+512 ----
    const int l1v = tid + 256, l2v = tid + 512;
    const int dy0 = tid / PW, dx0 = tid - dy0*PW;
    const int dy1 = l1v / PW, dx1 = l1v - dy1*PW;
    const int dy2 = l2v / PW, dx2 = l2v - dy2*PW;
    const bool w2  = (l2v < PN);
    const int sgh0 = h0-1+dy0, sgw0 = w0-1+dx0;
    const int sgh1 = h0-1+dy1, sgw1 = w0-1+dx1;
    const int sgh2 = h0-1+dy2, sgw2 = w0-1+dx2;
    const bool ok0 = ((unsigned)sgh0 < (unsigned)DIM_H) && ((unsigned)sgw0 < (unsigned)DIM_W);
    const bool ok1 = ((unsigned)sgh1 < (unsigned)DIM_H) && ((unsigned)sgw1 < (unsigned)DIM_W);
    const bool ok2 = w2 && ((unsigned)sgh2 < (unsigned)DIM_H) && ((unsigned)sgw2 < (unsigned)DIM_W);
    const unsigned soff0 = ok0 ? (unsigned)(sgh0*DIM_W + sgw0) : 0u;
    const unsigned soff1 = ok1 ? (unsigned)(sgh1*DIM_W + sgw1) : 0u;
    const unsigned soff2 = ok2 ? (unsigned)(sgh2*DIM_W + sgw2) : 0u;

    // yb = sig(200*(sig(yo)-0.5)) ~= sig(50*yo): max |err| ~4e-5 (validated R5+).
    // yb computed AT LOAD and packed half2(yb,tg): 3 u32 regs per staging set,
    // trans ops off the WRITEP->barrier critical path.
    auto LOADP = [&](int p, unsigned* sd){
        if ((unsigned)p < (unsigned)DIM_D) {       // uniform branch
            const unsigned pb = base + (unsigned)p*PL;
            float a0 = y_out[pb + soff0], c0 = y_tg[pb + soff0];
            float a1_ = y_out[pb + soff1], c1 = y_tg[pb + soff1];
            float a2_ = y_out[pb + soff2], c2 = y_tg[pb + soff2];
            float yo0 = ok0 ? a0 : -1e30f, tg0 = ok0 ? c0 : 0.f;
            float yo1 = ok1 ? a1_ : -1e30f, tg1 = ok1 ? c1 : 0.f;
            float yo2 = ok2 ? a2_ : -1e30f, tg2 = ok2 ? c2 : 0.f;
            sd[0] = h2u(__floats2half2_rn(rcpf_(1.f + ex2(-50.f*LOG2E*yo0)), tg0));
            sd[1] = h2u(__floats2half2_rn(rcpf_(1.f + ex2(-50.f*LOG2E*yo1)), tg1));
            sd[2] = h2u(__floats2half2_rn(rcpf_(1.f + ex2(-50.f*LOG2E*yo2)), tg2));
        } else { sd[0]=0u; sd[1]=0u; sd[2]=0u; }
    };
    auto WRITEP = [&](int slot, const unsigned* sd){
        ring[slot][tid] = sd[0];
        ring[slot][l1v] = sd[1];
        if (w2) ring[slot][l2v] = sd[2];
    };

    const int ty = tid >> 5, tx = tid & 31;
    const int gh = h0 + ty;
    const float2* xin2 = reinterpret_cast<const float2*>(x_in);
    const float2* yo2p = reinterpret_cast<const float2*>(y_out);
    const unsigned PL2 = PL >> 1;
    const unsigned cen2 = (base >> 1) + (unsigned)gh*(DIM_W/2) + (unsigned)(w0>>1) + (unsigned)tx;

    const float KC1 = 4.5399929762484854e-05f, KC2 = 7.2135410e-07f, KC3 = 3.0047e-08f;
    const float L0 = -88.f/26.f, L1 = 6.f/26.f, L2 = 3.f/26.f, L3 = 2.f/26.f;
    const float S30 = 47.f/256.f, S31 = 162.f/256.f;
    const float TFULL = 1.f + 6.f*KC1 + 12.f*KC2 + 8.f*KC3;
    const float Y4TH = 0.36787858f;   // y4 = step(acx < e^-1 - eps), validated R11

    float a_ce=0, a_tz=0, a_pzt=0, a_itzi=0, a_ipzti=0, a_ytg=0;
    float a_y1y2=0, a_y1=0;
    float2 aE1 = make_float2(0.f,0.f);   // (Σyb, Σy4)
    float2 aEx = make_float2(0.f,0.f);
    float2 aExx= make_float2(0.f,0.f);
    float dI0=0, dI1=0, dC0=0, dC1=0;

    // voxel math for depth d using planes A(d-1), B(d), C(d+1)
    auto VOXEL = [&](const PairH& A, const PairH& B, const PairH& C,
                     float2 xc2, float2 yoc2, int d){
        #pragma unroll
        for (int v = 0; v < 2; ++v) {
            __half2 q0 = __hadd2(A.u0[v], C.u0[v]);
            __half2 q1 = __hadd2(A.u1[v], C.u1[v]);
            __half2 q2 = __hadd2(A.u2[v], C.u2[v]);
            __half2 n1 = __hadd2(B.u1[v], q0);
            __half2 n2 = __hadd2(B.u2[v], q1);
            float m0x = __low2float(B.u0[v]), m0y = __high2float(B.u0[v]);
            float n1x = __low2float(n1), n1y = __high2float(n1);
            float n2x = __low2float(n2), n2y = __high2float(n2);
            float n3x = __low2float(q2), n3y = __high2float(q2);
            float acx = fmaf(KC3,n3x, fmaf(KC2,n2x, fmaf(KC1,n1x, m0x)));
            float act = fmaf(KC3,n3y, fmaf(KC2,n2y, fmaf(KC1,n1y, m0y)));
            float al  = fmaf(L3,n3x, fmaf(L2,n2x, fmaf(L1,n1x, L0*m0x)));
            float a1 = S30*(A.s1[v] + C.s1[v]) + S31*B.s1[v];
            float a2 = S30*(A.s2[v] + C.s2[v]) + S31*B.s2[v];
            float a3 = (S31*S31)*__low2float(__hsub2(A.u0[v], C.u0[v]))
                     + (S30*S31)*__low2float(__hsub2(A.u1[v], C.u1[v]))
                     + (S30*S30)*__low2float(__hsub2(A.u2[v], C.u2[v]));

            float t   = m0y;      // tg exact in f16 ({0,1})
            float ybc = m0x;
            float x   = v ? xc2.y  : xc2.x;
            float yo  = v ? yoc2.y : yoc2.x;

            // CE: one exp2 shared between softplus and sigmoid
            float ayo = fabsf(yo);
            float e1  = ex2(-LOG2E*ayo);
            float inv = rcpf_(1.f + e1);
            float yp  = (yo >= 0.f) ? inv : (1.f - inv);
            a_ce += fmaxf(yo, 0.f) - yo*t + LN2*lg2(1.f + e1);

            if (v) { dI1 += yp*t; dC1 += yp + t; }
            else   { dI0 += yp*t; dC0 += yp + t; }

            // t is binary: t*z + (1-t)*zinv needs ONE log via operand select
            bool tset = (t > 0.5f);
            float argx = tset ? acx : (TFULL - acx);
            float lx   = (-0.1f*LN2)*lg2(argx + 1e-6f);
            a_tz   += tset ? lx : 0.f;
            a_itzi += tset ? 0.f : lx;
            a_pzt   += yp      * (-0.1f*LN2)*lg2(act + 1e-6f);
            a_ipzti += (1.f-yp)* (-0.1f*LN2)*lg2((TFULL - act) + 1e-6f);
            a_ytg   += t;

            float y2 = __builtin_amdgcn_sqrtf(a1*a1 + a2*a2 + a3*a3 + 1e-6f);
            bool e1b = (al > 0.5f);
            a_y1y2 += e1b ? y2 : 0.f;
            a_y1   += e1b ? 1.f : 0.f;

            float y4 = (acx < Y4TH) ? 1.f : 0.f;
            aE1.x  += ybc;                     aE1.y  += y4;
            aEx.x   = fmaf(x,   ybc, aEx.x);   aEx.y   = fmaf(x,   y4, aEx.y);
            aExx.x  = fmaf(x*x, ybc, aExx.x);  aExx.y  = fmaf(x*x, y4, aExx.y);
        }
    };

    // ---- prologue: slot mapping slotOf(p) = (p-d0+1)&3 ----
    unsigned sA[3], sB[3];
    LOADP(d0-1, sA); WRITEP(0, sA);
    LOADP(d0,   sA); WRITEP(1, sA);
    LOADP(d0+1, sA); WRITEP(2, sA);
    LOADP(d0+2, sA);             // held for loop iter 0
    LOADP(d0+3, sB);
    float2 xc  = xin2[cen2 + (unsigned)d0*PL2];
    float2 yoc = yo2p[cen2 + (unsigned)d0*PL2];
    float2 xn  = xin2[cen2 + (unsigned)(d0+1)*PL2];
    float2 yon = yo2p[cen2 + (unsigned)(d0+1)*PL2];
    __syncthreads();
    PairH PA = calc_pair(ring[0], ty, tx);
    PairH PB = calc_pair(ring[1], ty, tx);
    PairH PC = calc_pair(ring[2], ty, tx);

    #pragma unroll
    for (int i = 0; i < DC; i += 2) {
        const int d = d0 + i;
        WRITEP((i+3)&3, sA);                   // plane d+2
        WRITEP(i&3, sB);                       // plane d+3 (overwrites d-1, already in PA)
        __syncthreads();
        if (i < DC-2) {                        // compile-time guard (full unroll)
            LOADP(d+4, sA);
            LOADP(d+5, sB);
        }
        // center prefetch for next iteration (clamped, always-valid)
        const int dp2 = min(d+2, DIM_D-1), dp3 = min(d+3, DIM_D-1);
        float2 xc2  = xin2[cen2 + (unsigned)dp2*PL2];
        float2 yoc2 = yo2p[cen2 + (unsigned)dp2*PL2];
        float2 xn2  = xin2[cen2 + (unsigned)dp3*PL2];
        float2 yon2 = yo2p[cen2 + (unsigned)dp3*PL2];

        PairH PD = calc_pair(ring[(i+3)&3], ty, tx);   // plane d+2
        VOXEL(PA, PB, PC, xc, yoc, d);
        PairH PE = calc_pair(ring[i&3], ty, tx);       // plane d+3
        VOXEL(PB, PC, PD, xn, yon, d+1);

        PA = PC; PB = PD; PC = PE;
        xc = xc2; yoc = yoc2; xn = xn2; yon = yon2;
    }

    // per-thread Σyp identity (before folds)
    float a_yp = (dC0 + dC1) - a_ytg;

    // fold dice across the wave's two ty rows
    dI0 += __shfl_xor(dI0, 32);  dI1 += __shfl_xor(dI1, 32);
    dC0 += __shfl_xor(dC0, 32);  dC1 += __shfl_xor(dC1, 32);

    float v[15] = {a_ce, a_tz, a_pzt, a_itzi, a_ipzti, a_yp, a_ytg, a_y1y2, a_y1,
                   aE1.x, aEx.x, aExx.x, aE1.y, aEx.y, aExx.y};
    #pragma unroll
    for (int k = 0; k < 15; ++k) {
        #pragma unroll
        for (int s = 32; s > 0; s >>= 1) v[k] += __shfl_xor(v[k], s);
    }

    __syncthreads();                 // all ring reads complete
    float* sl = (float*)ring;        // alias dead ring
    if (tid < 128) sl[tid] = 0.f;    // [0..63]=dice_i bins, [64..127]=dice_c bins
    __syncthreads();

    int wid = tid >> 6, lane = tid & 63;
    if (lane < 32) {
        atomicAdd(&sl[2*lane],       dI0);
        atomicAdd(&sl[2*lane+1],     dI1);
        atomicAdd(&sl[64 + 2*lane],  dC0);
        atomicAdd(&sl[64 + 2*lane+1],dC1);
    }
    if (lane == 0) {
        #pragma unroll
        for (int k = 0; k < 15; ++k) sl[128 + wid*16 + k] = v[k];
    }
    __syncthreads();

    if (tid < 15) {
        float s = sl[128+tid] + sl[144+tid] + sl[160+tid] + sl[176+tid];
        int gidx = (tid < 9) ? tid : (9 + (tid - 9)*2 + b);
        atomicAdd(&gacc[rep*24 + gidx], (double)s);
    }
    if (tid < 64) {
        atomicAdd(&dice_i[b*DIM_W + w0 + tid], sl[tid]);
        atomicAdd(&dice_c[b*DIM_W + w0 + tid], sl[64 + tid]);
    }
}

__global__ __launch_bounds__(256) void lumen_final(
    const double* __restrict__ gacc,
    const float* __restrict__ dice_i, const float* __restrict__ dice_c,
    const float* __restrict__ gamma_ace, float* __restrict__ out)
{
    __shared__ float red[4];
    __shared__ double gs[24];
    int tid = threadIdx.x;
    if (tid < 24) {
        double sr = 0.0;
        for (int r = 0; r < NREP; ++r) sr += gacc[r*24 + tid];
        gs[tid] = sr;
    }
    float s = 0.f;
    for (int i = tid; i < 2*DIM_W; i += 256) {
        float I = dice_i[i], C = dice_c[i];
        s += 1.f - 2.f*I/(C + 1e-6f);
    }
    #pragma unroll
    for (int sh = 32; sh > 0; sh >>= 1) s += __shfl_xor(s, sh);
    if ((tid & 63) == 0) red[tid >> 6] = s;
    __syncthreads();
    if (tid == 0) {
        double dice_sum = (double)red[0] + red[1] + red[2] + red[3];
        double loss_dice = dice_sum / (2.0*DIM_W);
        const double Nb = (double)DIM_D * DIM_H * DIM_W;
        const double Nt = 2.0 * Nb;
        const double eps = 1e-6;
        double loss_ce = gs[0]/Nt;
        double dl1 = (gs[1]/Nt) / ((gs[6]/Nt) + eps);
        double dl2 = (gs[2]/Nt) / ((gs[5]/Nt) + eps);
        double dl3 = (gs[3]/Nt) / (((Nt - gs[6])/Nt) + eps);
        double dl4 = (gs[4]/Nt) / (((Nt - gs[5])/Nt) + eps);
        double loss_dt = dl1 + dl2 + dl3 + dl4;
        double E1n = 0.0, E2n = 0.0;
        for (int bb = 0; bb < 2; ++bb) {
            double S1 = gs[9+bb],  Sx = gs[11+bb], Sxx = gs[13+bb];
            double l1 = (Sx/Nb) / ((S1/Nb) + eps);
            E1n += Sxx - 2.0*l1*Sx + l1*l1*S1;
            double Q1 = gs[15+bb], Qx = gs[17+bb], Qxx = gs[19+bb];
            double l2 = (Qx/Nb) / ((Q1/Nb) + eps);
            E2n += Qxx - 2.0*l2*Qx + l2*l2*Q1;
        }
        double E1 = (E1n/Nt) / (((gs[9]+gs[10])/Nt) + eps);
        double E2 = (E2n/Nt) / (((gs[15]+gs[16])/Nt) + eps);
        double S  = (gs[7]/Nt) / ((gs[8]/Nt) + eps);
        double loss_ace = E1 + E2 + (double)gamma_ace[0]*S;
        out[0] = (float)(loss_ce + loss_dice + 0.1*loss_dt + 0.1*loss_ace);
    }
}

extern "C" void kernel_launch(void* const* d_in, const int* in_sizes, int n_in,
                              void* d_out, int out_size, void* d_ws, size_t ws_size,
                              hipStream_t stream) {
    const float* x_in  = (const float*)d_in[0];
    const float* y_out = (const float*)d_in[1];
    const float* y_tg  = (const float*)d_in[2];
    const float* gamma = (const float*)d_in[4];
    float* out = (float*)d_out;

    double* gacc  = (double*)d_ws;                       // 16 replicas x 24 doubles = 3072 B
    float* dice_i = (float*)((char*)d_ws + 4096);        // 384 floats
    float* dice_c = (float*)((char*)d_ws + 6144);        // 384 floats

    hipMemsetAsync(d_ws, 0, 8192, stream);

    dim3 grid(DIM_W/TW, DIM_H/TH, 2*(DIM_D/DC));
    lumen_main<<<grid, 256, 0, stream>>>(x_in, y_out, y_tg, gacc, dice_i, dice_c);
    lumen_final<<<1, 256, 0, stream>>>(gacc, dice_i, dice_c, gamma, out);
}

// Round 17
// 71.417 us; speedup vs baseline: 1.1407x; 1.1407x over previous
//
#include <hip/hip_runtime.h>
#include <hip/hip_bf16.h>
#include <hip/hip_fp16.h>

#define TH 8
#define TW 64        // w extent per tile (2 voxels per lane)
#define DC 8
#define PH (TH+2)    // 10
#define PW (TW+2)    // 66
#define PN (PH*PW)   // 660

#define DIM_D 128
#define DIM_H 192
#define DIM_W 192
#define NREP 16      // gacc replicas (atomic spread)

#define LOG2E 1.4426950408889634f
#define LN2   0.6931471805599453f

__device__ __forceinline__ float ex2(float x){ return __builtin_amdgcn_exp2f(x); }
__device__ __forceinline__ float lg2(float x){ return __builtin_amdgcn_logf(x); }
__device__ __forceinline__ float rcpf_(float x){ return __builtin_amdgcn_rcpf(x); }
__device__ __forceinline__ __half2 bch2(unsigned u){ return __builtin_bit_cast(__half2, u); }
__device__ __forceinline__ unsigned h2u(__half2 h){ return __builtin_bit_cast(unsigned, h); }
// pack the low (yb) halves of two half2s -> (a.lo, b.lo)
__device__ __forceinline__ __half2 pklo(__half2 a, __half2 b){
    return __halves2half2(__low2half(a), __low2half(b));
}

// packed per-plane state: u* are (yb,tg) half2 per voxel; s1p/s2p/s3p are
// voxel-paired yb-only Sobel partials (lane = voxel). 9 u32 regs/plane.
// f16 yb (rel err 5e-4) -> z err ~5e-5; Sobel f16 err ~1e-3 -> final ~3e-6.
struct PairH { __half2 u0[2], u1[2], u2[2]; __half2 s1p, s2p, s3p; };

__device__ __forceinline__ PairH calc_pair(const unsigned* __restrict__ spu, int ty, int tx)
{
    __half2 c[3][4];
    #pragma unroll
    for (int r = 0; r < 3; ++r) {
        const unsigned* row = spu + (ty+r)*PW + 2*tx;   // 8B-aligned (index even)
        uint2 lo = *reinterpret_cast<const uint2*>(row);
        uint2 hi = *reinterpret_cast<const uint2*>(row + 2);
        c[r][0]=bch2(lo.x); c[r][1]=bch2(lo.y); c[r][2]=bch2(hi.x); c[r][3]=bch2(hi.y);
    }
    __half2 s[4], m[4], dv[4];
    #pragma unroll
    for (int j = 0; j < 4; ++j) {
        s[j]  = __hadd2(c[0][j], c[2][j]);
        m[j]  = c[1][j];
        dv[j] = __hsub2(c[0][j], c[2][j]);
    }
    PairH P;
    __half2 mm02 = __hadd2(m[0], m[2]), mm13 = __hadd2(m[1], m[3]);
    P.u0[0] = m[1];                 P.u0[1] = m[2];
    P.u1[0] = __hadd2(s[1], mm02);  P.u1[1] = __hadd2(s[2], mm13);
    P.u2[0] = __hadd2(s[0], s[2]);  P.u2[1] = __hadd2(s[1], s[3]);

    const __half2 S30h = __float2half2_rn(47.f/256.f);
    const __half2 S31h = __float2half2_rn(162.f/256.f);
    // s1 (horizontal): lane v = S30*(s[v]-s[v+2]) + S31*(m[v]-m[v+2])  [yb only]
    P.s1p = __hfma2(S30h, __hsub2(pklo(s[0],s[1]), pklo(s[2],s[3])),
                    __hmul2(S31h, __hsub2(pklo(m[0],m[1]), pklo(m[2],m[3]))));
    // s2 (vertical): lane v = S30*(dv[v]+dv[v+2]) + S31*dv[v+1]
    P.s2p = __hfma2(S30h, __hadd2(pklo(dv[0],dv[1]), pklo(dv[2],dv[3])),
                    __hmul2(S31h, pklo(dv[1],dv[2])));
    // s3 (plane weight for d-Sobel): S31^2*u0 + S30*S31*u1 + S30^2*u2
    const __half2 K33 = __float2half2_rn((162.f/256.f)*(162.f/256.f));
    const __half2 K31 = __float2half2_rn((47.f/256.f)*(162.f/256.f));
    const __half2 K11 = __float2half2_rn((47.f/256.f)*(47.f/256.f));
    P.s3p = __hfma2(K33, pklo(P.u0[0],P.u0[1]),
            __hfma2(K31, pklo(P.u1[0],P.u1[1]),
            __hmul2(K11, pklo(P.u2[0],P.u2[1]))));
    return P;
}

__global__ __launch_bounds__(256) void lumen_main(
    const float* __restrict__ x_in, const float* __restrict__ y_out,
    const float* __restrict__ y_tg, double* __restrict__ gacc,
    float* __restrict__ dice_i, float* __restrict__ dice_c)
{
    __shared__ unsigned ring[4][PN];   // half2-packed (yb,tg); 10,560 B

    const int tid = threadIdx.x;
    const int b  = blockIdx.z >> 4;              // 16 d-tiles of DC=8
    const int d0 = (blockIdx.z & 15) * DC;
    const int h0 = blockIdx.y * TH;
    const int w0 = blockIdx.x * TW;
    const unsigned base = (unsigned)b * (unsigned)(DIM_D*DIM_H*DIM_W);
    const unsigned PL = DIM_H*DIM_W;
    const int rep = (blockIdx.x + gridDim.x*(blockIdx.y + gridDim.y*blockIdx.z)) & (NREP-1);

    // ---- staging map: thread handles halo elems tid, tid+256, tid+512 ----
    const int l1v = tid + 256, l2v = tid + 512;
    const int dy0 = tid / PW, dx0 = tid - dy0*PW;
    const int dy1 = l1v / PW, dx1 = l1v - dy1*PW;
    const int dy2 = l2v / PW, dx2 = l2v - dy2*PW;
    const bool w2  = (l2v < PN);
    const int sgh0 = h0-1+dy0, sgw0 = w0-1+dx0;
    const int sgh1 = h0-1+dy1, sgw1 = w0-1+dx1;
    const int sgh2 = h0-1+dy2, sgw2 = w0-1+dx2;
    const bool ok0 = ((unsigned)sgh0 < (unsigned)DIM_H) && ((unsigned)sgw0 < (unsigned)DIM_W);
    const bool ok1 = ((unsigned)sgh1 < (unsigned)DIM_H) && ((unsigned)sgw1 < (unsigned)DIM_W);
    const bool ok2 = w2 && ((unsigned)sgh2 < (unsigned)DIM_H) && ((unsigned)sgw2 < (unsigned)DIM_W);
    const unsigned soff0 = ok0 ? (unsigned)(sgh0*DIM_W + sgw0) : 0u;
    const unsigned soff1 = ok1 ? (unsigned)(sgh1*DIM_W + sgw1) : 0u;
    const unsigned soff2 = ok2 ? (unsigned)(sgh2*DIM_W + sgw2) : 0u;

    // yb = sig(200*(sig(yo)-0.5)) ~= sig(50*yo): max |err| ~4e-5 (validated R5+).
    // packed at load: 3 u32 staging regs; trans off the write->barrier path.
    // yo=-1e30 -> ex2(+inf) -> rcp = 0 (zero padding falls out).
    unsigned sd[3];
    auto LOADP = [&](int p){
        if ((unsigned)p < (unsigned)DIM_D) {       // uniform branch
            const unsigned pb = base + (unsigned)p*PL;
            float a0 = y_out[pb + soff0], c0 = y_tg[pb + soff0];
            float a1_ = y_out[pb + soff1], c1 = y_tg[pb + soff1];
            float a2_ = y_out[pb + soff2], c2 = y_tg[pb + soff2];
            float yo0 = ok0 ? a0 : -1e30f, tg0 = ok0 ? c0 : 0.f;
            float yo1 = ok1 ? a1_ : -1e30f, tg1 = ok1 ? c1 : 0.f;
            float yo2 = ok2 ? a2_ : -1e30f, tg2 = ok2 ? c2 : 0.f;
            sd[0] = h2u(__floats2half2_rn(rcpf_(1.f + ex2(-50.f*LOG2E*yo0)), tg0));
            sd[1] = h2u(__floats2half2_rn(rcpf_(1.f + ex2(-50.f*LOG2E*yo1)), tg1));
            sd[2] = h2u(__floats2half2_rn(rcpf_(1.f + ex2(-50.f*LOG2E*yo2)), tg2));
        } else { sd[0]=0u; sd[1]=0u; sd[2]=0u; }
    };
    auto WRITEP = [&](int slot){
        ring[slot][tid] = sd[0];
        ring[slot][l1v] = sd[1];
        if (w2) ring[slot][l2v] = sd[2];
    };

    const int ty = tid >> 5, tx = tid & 31;
    const int gh = h0 + ty;
    const float2* xin2 = reinterpret_cast<const float2*>(x_in);
    const float2* yo2p = reinterpret_cast<const float2*>(y_out);
    const unsigned PL2 = PL >> 1;
    const unsigned cen2 = (base >> 1) + (unsigned)gh*(DIM_W/2) + (unsigned)(w0>>1) + (unsigned)tx;

    const float KC1 = 4.5399929762484854e-05f, KC2 = 7.2135410e-07f, KC3 = 3.0047e-08f;
    const float L0 = -88.f/26.f, L1 = 6.f/26.f, L2 = 3.f/26.f, L3 = 2.f/26.f;
    const float TFULL = 1.f + 6.f*KC1 + 12.f*KC2 + 8.f*KC3;
    const float Y4TH = 0.36787858f;   // y4 = step(acx < e^-1 - eps), validated R11
    const __half2 S30h2 = __float2half2_rn(47.f/256.f);
    const __half2 S31h2 = __float2half2_rn(162.f/256.f);

    // ---- prologue: planes d0-1, d0, d0+1 staged; d0+2 in regs ----
    LOADP(d0-1); WRITEP(3);
    LOADP(d0  ); WRITEP(0);
    LOADP(d0+1); WRITEP(1);
    LOADP(d0+2);
    float2 xc  = xin2[cen2 + (unsigned)d0*PL2];
    float2 yoc = yo2p[cen2 + (unsigned)d0*PL2];
    __syncthreads();
    PairH PA = calc_pair(ring[3], ty, tx);
    PairH PB = calc_pair(ring[0], ty, tx);

    float a_ce=0, a_tz=0, a_pzt=0, a_itzi=0, a_ipzti=0, a_ytg=0;
    float a_y1y2=0, a_y1=0;
    float2 aE1 = make_float2(0.f,0.f);   // (Σyb, Σy4)
    float2 aEx = make_float2(0.f,0.f);
    float2 aExx= make_float2(0.f,0.f);
    float dI0=0, dI1=0, dC0=0, dC1=0;

    #pragma unroll 2
    for (int i = 0; i < DC; ++i) {
        const int d = d0 + i;
        WRITEP((i+2)&3);                       // plane d+2 from staging regs
        __syncthreads();
        LOADP(d+3);                            // prefetch plane d+3 (hidden under math)
        const int dn = min(d+1, DIM_D-1);
        float2 xn  = xin2[cen2 + (unsigned)dn*PL2];
        float2 yon = yo2p[cen2 + (unsigned)dn*PL2];

        PairH PC = calc_pair(ring[(i+1)&3], ty, tx);   // plane d+1

        // Sobel magnitudes for both voxels (paired f16)
        __half2 a1p = __hfma2(S30h2, __hadd2(PA.s1p, PC.s1p), __hmul2(S31h2, PB.s1p));
        __half2 a2p = __hfma2(S30h2, __hadd2(PA.s2p, PC.s2p), __hmul2(S31h2, PB.s2p));
        __half2 a3p = __hsub2(PA.s3p, PC.s3p);

        #pragma unroll
        for (int v = 0; v < 2; ++v) {
            __half2 q0 = __hadd2(PA.u0[v], PC.u0[v]);
            __half2 q1 = __hadd2(PA.u1[v], PC.u1[v]);
            __half2 q2 = __hadd2(PA.u2[v], PC.u2[v]);
            __half2 n1 = __hadd2(PB.u1[v], q0);
            __half2 n2 = __hadd2(PB.u2[v], q1);
            float m0x = __low2float(PB.u0[v]), m0y = __high2float(PB.u0[v]);
            float n1x = __low2float(n1), n1y = __high2float(n1);
            float n2x = __low2float(n2), n2y = __high2float(n2);
            float n3x = __low2float(q2), n3y = __high2float(q2);
            float acx = fmaf(KC3,n3x, fmaf(KC2,n2x, fmaf(KC1,n1x, m0x)));
            float act = fmaf(KC3,n3y, fmaf(KC2,n2y, fmaf(KC1,n1y, m0y)));
            float al  = fmaf(L3,n3x, fmaf(L2,n2x, fmaf(L1,n1x, L0*m0x)));
            float a1 = v ? __high2float(a1p) : __low2float(a1p);
            float a2 = v ? __high2float(a2p) : __low2float(a2p);
            float a3 = v ? __high2float(a3p) : __low2float(a3p);

            float t   = m0y;      // tg exact binary in f16
            float ybc = m0x;
            float x   = v ? xc.y  : xc.x;
            float yo  = v ? yoc.y : yoc.x;

            // CE: one exp2 shared between softplus and sigmoid
            float ayo = fabsf(yo);
            float e1  = ex2(-LOG2E*ayo);
            float inv = rcpf_(1.f + e1);
            float yp  = (yo >= 0.f) ? inv : (1.f - inv);
            a_ce += fmaxf(yo, 0.f) - yo*t + LN2*lg2(1.f + e1);

            if (v) { dI1 += yp*t; dC1 += yp + t; }
            else   { dI0 += yp*t; dC0 += yp + t; }

            bool tset = (t > 0.5f);
            // acx side: t binary -> only selected branch contributes (EXACT)
            float argx = tset ? acx : (TFULL - acx);
            float lx   = (-0.1f*LN2)*lg2(argx + 1e-6f);
            a_tz   += tset ? lx : 0.f;
            a_itzi += tset ? 0.f : lx;
            // act side: log of tiny side + linear for near-1 side (err < 4e-8)
            float sm_arg = tset ? (TFULL - act) : act;
            float sm_log = (-0.1f*LN2)*lg2(sm_arg + 1e-6f);
            float lin    = -0.1f*((tset ? (act - 1.f) : (TFULL - 1.f - act)) + 1e-6f);
            a_pzt   += yp      * (tset ? lin    : sm_log);
            a_ipzti += (1.f-yp)* (tset ? sm_log : lin);
            a_ytg   += t;

            float y2 = __builtin_amdgcn_sqrtf(fmaf(a1,a1, fmaf(a2,a2, fmaf(a3,a3, 1e-6f))));
            bool e1b = (al > 0.5f);
            a_y1y2 += e1b ? y2 : 0.f;
            a_y1   += e1b ? 1.f : 0.f;

            float y4 = (acx < Y4TH) ? 1.f : 0.f;
            aE1.x  += ybc;                     aE1.y  += y4;
            aEx.x   = fmaf(x,   ybc, aEx.x);   aEx.y   = fmaf(x,   y4, aEx.y);
            aExx.x  = fmaf(x*x, ybc, aExx.x);  aExx.y  = fmaf(x*x, y4, aExx.y);
        }

        PA = PB; PB = PC;
        xc = xn; yoc = yon;
    }

    // per-thread Σyp identity (before folds)
    float a_yp = (dC0 + dC1) - a_ytg;

    // fold dice across the wave's two ty rows
    dI0 += __shfl_xor(dI0, 32);  dI1 += __shfl_xor(dI1, 32);
    dC0 += __shfl_xor(dC0, 32);  dC1 += __shfl_xor(dC1, 32);

    float v[15] = {a_ce, a_tz, a_pzt, a_itzi, a_ipzti, a_yp, a_ytg, a_y1y2, a_y1,
                   aE1.x, aEx.x, aExx.x, aE1.y, aEx.y, aExx.y};
    #pragma unroll
    for (int k = 0; k < 15; ++k) {
        #pragma unroll
        for (int s = 32; s > 0; s >>= 1) v[k] += __shfl_xor(v[k], s);
    }

    __syncthreads();                 // all ring reads complete
    float* sl = (float*)ring;        // alias dead ring
    if (tid < 128) sl[tid] = 0.f;    // [0..63]=dice_i bins, [64..127]=dice_c bins
    __syncthreads();

    int wid = tid >> 6, lane = tid & 63;
    if (lane < 32) {
        atomicAdd(&sl[2*lane],       dI0);
        atomicAdd(&sl[2*lane+1],     dI1);
        atomicAdd(&sl[64 + 2*lane],  dC0);
        atomicAdd(&sl[64 + 2*lane+1],dC1);
    }
    if (lane == 0) {
        #pragma unroll
        for (int k = 0; k < 15; ++k) sl[128 + wid*16 + k] = v[k];
    }
    __syncthreads();

    if (tid < 15) {
        float s = sl[128+tid] + sl[144+tid] + sl[160+tid] + sl[176+tid];
        int gidx = (tid < 9) ? tid : (9 + (tid - 9)*2 + b);
        atomicAdd(&gacc[rep*24 + gidx], (double)s);
    }
    if (tid < 64) {
        atomicAdd(&dice_i[b*DIM_W + w0 + tid], sl[tid]);
        atomicAdd(&dice_c[b*DIM_W + w0 + tid], sl[64 + tid]);
    }
}

__global__ __launch_bounds__(256) void lumen_final(
    const double* __restrict__ gacc,
    const float* __restrict__ dice_i, const float* __restrict__ dice_c,
    const float* __restrict__ gamma_ace, float* __restrict__ out)
{
    __shared__ float red[4];
    __shared__ double gs[24];
    int tid = threadIdx.x;
    if (tid < 24) {
        double sr = 0.0;
        for (int r = 0; r < NREP; ++r) sr += gacc[r*24 + tid];
        gs[tid] = sr;
    }
    float s = 0.f;
    for (int i = tid; i < 2*DIM_W; i += 256) {
        float I = dice_i[i], C = dice_c[i];
        s += 1.f - 2.f*I/(C + 1e-6f);
    }
    #pragma unroll
    for (int sh = 32; sh > 0; sh >>= 1) s += __shfl_xor(s, sh);
    if ((tid & 63) == 0) red[tid >> 6] = s;
    __syncthreads();
    if (tid == 0) {
        double dice_sum = (double)red[0] + red[1] + red[2] + red[3];
        double loss_dice = dice_sum / (2.0*DIM_W);
        const double Nb = (double)DIM_D * DIM_H * DIM_W;
        const double Nt = 2.0 * Nb;
        const double eps = 1e-6;
        double loss_ce = gs[0]/Nt;
        double dl1 = (gs[1]/Nt) / ((gs[6]/Nt) + eps);
        double dl2 = (gs[2]/Nt) / ((gs[5]/Nt) + eps);
        double dl3 = (gs[3]/Nt) / (((Nt - gs[6])/Nt) + eps);
        double dl4 = (gs[4]/Nt) / (((Nt - gs[5])/Nt) + eps);
        double loss_dt = dl1 + dl2 + dl3 + dl4;
        double E1n = 0.0, E2n = 0.0;
        for (int bb = 0; bb < 2; ++bb) {
            double S1 = gs[9+bb],  Sx = gs[11+bb], Sxx = gs[13+bb];
            double l1 = (Sx/Nb) / ((S1/Nb) + eps);
            E1n += Sxx - 2.0*l1*Sx + l1*l1*S1;
            double Q1 = gs[15+bb], Qx = gs[17+bb], Qxx = gs[19+bb];
            double l2 = (Qx/Nb) / ((Q1/Nb) + eps);
            E2n += Qxx - 2.0*l2*Qx + l2*l2*Q1;
        }
        double E1 = (E1n/Nt) / (((gs[9]+gs[10])/Nt) + eps);
        double E2 = (E2n/Nt) / (((gs[15]+gs[16])/Nt) + eps);
        double S  = (gs[7]/Nt) / ((gs[8]/Nt) + eps);
        double loss_ace = E1 + E2 + (double)gamma_ace[0]*S;
        out[0] = (float)(loss_ce + loss_dice + 0.1*loss_dt + 0.1*loss_ace);
    }
}

extern "C" void kernel_launch(void* const* d_in, const int* in_sizes, int n_in,
                              void* d_out, int out_size, void* d_ws, size_t ws_size,
                              hipStream_t stream) {
    const float* x_in  = (const float*)d_in[0];
    const float* y_out = (const float*)d_in[1];
    const float* y_tg  = (const float*)d_in[2];
    const float* gamma = (const float*)d_in[4];
    float* out = (float*)d_out;

    double* gacc  = (double*)d_ws;                       // 16 replicas x 24 doubles = 3072 B
    float* dice_i = (float*)((char*)d_ws + 4096);        // 384 floats
    float* dice_c = (float*)((char*)d_ws + 6144);        // 384 floats

    hipMemsetAsync(d_ws, 0, 8192, stream);

    dim3 grid(DIM_W/TW, DIM_H/TH, 2*(DIM_D/DC));
    lumen_main<<<grid, 256, 0, stream>>>(x_in, y_out, y_tg, gacc, dice_i, dice_c);
    lumen_final<<<1, 256, 0, stream>>>(gacc, dice_i, dice_c, gamma, out);
}